// Round 14
// baseline (70.074 us; speedup 1.0000x reference)
//
#include <hip/hip_runtime.h>
#include <math.h>

// HierarchicalPooling collapsed pipeline, round 14.
// N=32768, D=256, S=4, H=8, DH=32, CS=3276, C=11.
// R13 win: pass-2 MFMA via ds_read_b64_tr_b16 (69.4 -> 61.8us). Remaining
// cost is spread across 8 launches (~2-3us ramp/drain each) + small kernels.
// R14: consolidate tail: kp+ko -> kpo2 (44x1024, pooled stays in LDS),
// kf1+kf2b -> kfc (R8-proven 11x1024, writes CF2), kbc2 -> kbc3 (R8-proven).
// ka/kbd10/ke2 byte-identical to R13. 8 -> 6 launches.

namespace {
constexpr int N   = 32768;
constexpr int CS  = 3276;
constexpr int CPC = 52;                // 64-node chunks per full cluster
constexpr int NB  = CPC*10 + 1;        // 521 blocks

// ws layout (float offsets); total ~17.5 MB
constexpr size_t CQ_OFF   = 0;                               // 32
constexpr size_t WQBF_OFF = 32;                              // 1024 uint4 B-fragments
constexpr size_t PART_OFF = WQBF_OFF + 4096;                 // NB*8192 chunk xw partials
constexpr size_t PS_OFF   = PART_OFF + (size_t)NB*8192;      // 11*32 sum-exp (atomic)
constexpr size_t XW_OFF   = PS_OFF + 352;                    // 11*8192 normalized xw
constexpr size_t OL_OFF   = XW_OFF + 90112;                  // 11*1024 out rows
constexpr size_t CF2_OFF  = OL_OFF + 11264;                  // 11*256 final rows
}

typedef __attribute__((ext_vector_type(8))) short short8;
typedef __attribute__((ext_vector_type(4))) float f32x4;

__device__ __forceinline__ unsigned f2bf(float f){    // f32 -> bf16 bits, RNE
  unsigned u = __float_as_uint(f);
  unsigned r = u + 0x7FFFu + ((u >> 16) & 1u);
  return r >> 16;
}

// ---- KA: wq rows -> bf16 B-fragments (packed via LDS); cq; PS zero. (R10-proven)
__global__ __launch_bounds__(256) void ka(const float* __restrict__ Wk, const float* __restrict__ bk,
                                          const float* __restrict__ pq, float* __restrict__ ws){
  int b = blockIdx.x, t = threadIdx.x;
  const float scale = 0.17677669529663688f;   // 32^-0.5
  if (b < 32){
    __shared__ float row[256];
    int s = b >> 3, h = b & 7;
    const float* wrow = Wk + ((size_t)s<<16) + (size_t)t*256 + h*32;
    const float* q = pq + (s*8 + h)*32;
    float a = 0.f;
#pragma unroll
    for (int j=0;j<32;j++) a = fmaf(wrow[j], q[j], a);
    row[t] = a*scale;
    __syncthreads();
    if (t < 32){
      int ks = t & 7, kg2 = t >> 3;
      const float* src = row + ks*32 + kg2*8;
      uint4 p;
      p.x = f2bf(src[0]) | (f2bf(src[1]) << 16);
      p.y = f2bf(src[2]) | (f2bf(src[3]) << 16);
      p.z = f2bf(src[4]) | (f2bf(src[5]) << 16);
      p.w = f2bf(src[6]) | (f2bf(src[7]) << 16);
      int Nt = b >> 4, l15b = b & 15;
      ((uint4*)(ws + WQBF_OFF))[(size_t)(Nt*8 + ks)*64 + l15b + 16*kg2] = p;
    }
  } else {
    if (t < 32){
      int s = t >> 3, h = t & 7;
      const float* br = bk + s*256 + h*32;
      const float* q = pq + t*32;
      float a = 0.f;
#pragma unroll
    for (int j=0;j<32;j++) a = fmaf(br[j], q[j], a);
      ws[CQ_OFF + t] = a*scale;
    }
    for (int i = t; i < 352; i += 256) ws[PS_OFF + i] = 0.f;   // zero atomic targets
  }
}

// ---- KBD10: MFMA scores + exp + PS atomics + MFMA xw chunk partials. (R13-proven)
__global__ __launch_bounds__(512,4) void kbd10(const float* __restrict__ x, float* __restrict__ ws){
  int b = blockIdx.x, t = threadIdx.x;
  int c  = (b < 520) ? (b / CPC) : 10;
  int wi = (b < 520) ? (b % CPC) : 0;
  int n0 = c*CS + wi*64;
  int n1 = min(n0 + 64, min((c+1)*CS, N));
  int cnt = n1 - n0;                    // 64, 12 (cluster tails), or 8 (cluster 10)

  __shared__ __align__(16) unsigned short xtb[64*264]; // 33.8KB bf16 tile, row stride 528B
  __shared__ __align__(16) unsigned short swT[32*72];  // 4.6KB bf16 weights [sh][j], stride 144B
  __shared__ float psb[16*32];

  int wv = t >> 6, lane = t & 63;
  int Mt = wv & 3, Nt = wv >> 2;
  int l15 = lane & 15, kg = lane >> 4;
  int arow = Mt*16 + l15;
  uint4 bfr[8];
  const uint4* WQBF4 = (const uint4*)(ws + WQBF_OFF);
#pragma unroll
  for (int ks=0; ks<8; ++ks) bfr[ks] = WQBF4[(size_t)(Nt*8 + ks)*64 + lane];
  float cqv = ws[CQ_OFF + Nt*16 + l15];
  int shc = Nt*16 + l15;

  // stage 64 rows as bf16; rows >= N zero-filled (NaN-safe for pass2 MFMA)
  const float4* X4 = (const float4*)x;
#pragma unroll
  for (int k=0;k<8;k++){
    int f = t + k*512;
    int j = f >> 6, c4 = f & 63;
    float4 v = (n0 + j < N) ? X4[(size_t)(n0+j)*64 + c4] : make_float4(0.f,0.f,0.f,0.f);
    uint2 p;
    p.x = f2bf(v.x) | (f2bf(v.y) << 16);
    p.y = f2bf(v.z) | (f2bf(v.w) << 16);
    *(uint2*)(xtb + j*264 + c4*4) = p;
  }
  __syncthreads();

  // ---- pass 1: scores via 8x mfma_f32_16x16x32_bf16
  f32x4 acc1 = {0.f, 0.f, 0.f, 0.f};
#pragma unroll
  for (int ks=0; ks<8; ++ks){
    union { uint4 q; short8 v; } A, B;
    A.q = *(const uint4*)(xtb + arow*264 + ks*32 + kg*8);
    B.q = bfr[ks];
    acc1 = __builtin_amdgcn_mfma_f32_16x16x32_bf16(A.v, B.v, acc1, 0, 0, 0);
  }
  // epilogue: weights (bf16) -> swT[sh][j]; zero for j >= cnt; chunk sums.
  {
    float ev[4];
    float s4 = 0.f;
#pragma unroll
    for (int r=0;r<4;r++){
      int jl = Mt*16 + kg*4 + r;
      float e = (jl < cnt) ? __expf(acc1[r] + cqv) : 0.f;
      ev[r] = e; s4 += e;
    }
    uint2 wp;
    wp.x = f2bf(ev[0]) | (f2bf(ev[1]) << 16);
    wp.y = f2bf(ev[2]) | (f2bf(ev[3]) << 16);
    *(uint2*)(swT + (size_t)shc*72 + Mt*16 + kg*4) = wp;
    psb[(Mt*4 + kg)*32 + shc] = s4;
  }
  __syncthreads();
  if (t < 32){
    float S = 0.f;
#pragma unroll
    for (int k=0;k<16;k++) S += psb[k*32 + t];
    unsafeAtomicAdd(ws + PS_OFF + (size_t)c*32 + t, S);
  }

  // ---- pass 2: O[sh][d] = sum_j w[j][sh]*x[j][d] via MFMA.
  int Mt2 = wv & 1, Nq = wv >> 1;
  union FR { uint4 q; short8 v; };
  FR a0, a1;
  a0.q = *(const uint4*)(swT + (size_t)(Mt2*16 + l15)*72 + kg*8);
  a1.q = *(const uint4*)(swT + (size_t)(Mt2*16 + l15)*72 + 32 + kg*8);
  unsigned xb = (unsigned)(size_t)&xtb[0];
  unsigned va = xb + (unsigned)(kg*4224 + (l15>>2)*528 + (l15&3)*8 + Nq*128);
  unsigned long long tr[4][2][2];
#pragma unroll
  for (int i=0;i<4;i++){
#pragma unroll
    for (int k2=0;k2<2;k2++){
      asm volatile("ds_read_b64_tr_b16 %0, %2 offset:%c3\n\t"
                   "ds_read_b64_tr_b16 %1, %2 offset:%c4"
                   : "=v"(tr[i][k2][0]), "=v"(tr[i][k2][1])
                   : "v"(va), "i"(i*32 + k2*16896), "i"(i*32 + k2*16896 + 2112));
    }
  }
  asm volatile("s_waitcnt lgkmcnt(0)" ::: "memory");
  __builtin_amdgcn_sched_barrier(0);
  f32x4 o[4] = {{0.f,0.f,0.f,0.f},{0.f,0.f,0.f,0.f},{0.f,0.f,0.f,0.f},{0.f,0.f,0.f,0.f}};
#pragma unroll
  for (int i=0;i<4;i++){
#pragma unroll
    for (int k2=0;k2<2;k2++){
      FR Bf;
      Bf.q.x = (unsigned)(tr[i][k2][0] & 0xffffffffULL);
      Bf.q.y = (unsigned)(tr[i][k2][0] >> 32);
      Bf.q.z = (unsigned)(tr[i][k2][1] & 0xffffffffULL);
      Bf.q.w = (unsigned)(tr[i][k2][1] >> 32);
      o[i] = __builtin_amdgcn_mfma_f32_16x16x32_bf16(k2 ? a1.v : a0.v, Bf.v, o[i], 0, 0, 0);
    }
  }
  // store partials: C layout col(d)=l15, row(sh)=kg*4+r
  float* pr = ws + PART_OFF + (size_t)b*8192;
#pragma unroll
  for (int i=0;i<4;i++){
    int dcol = Nq*64 + i*16 + l15;
#pragma unroll
    for (int r=0;r<4;r++)
      pr[(size_t)(Mt2*16 + kg*4 + r)*256 + dcol] = o[i][r];
  }
}

// ---- KE2: sum chunk partials / PS -> xw[c][sh][d]. 352 blocks (R7-proven).
__global__ __launch_bounds__(256) void ke2(float* __restrict__ ws){
  int b = blockIdx.x, t = threadIdx.x;
  int c = b >> 5, sh = b & 31;
  int nch = (c < 10) ? CPC : 1;
  int cb  = (c < 10) ? c*CPC : 520;
  float rden = 1.0f / ws[PS_OFF + (size_t)c*32 + sh];
  const float* part = ws + PART_OFF + (size_t)sh*256 + t;
  float a = 0.f;
  for (int k=0;k<nch;k++) a += part[(size_t)(cb+k)*8192];
  ws[XW_OFF + (size_t)c*8192 + (size_t)sh*256 + t] = a * rden;
}

// ---- KPO2: fused pooled -> out per (c,s). 44 blocks x 1024 threads.
// Same per-thread work shapes as the R7 kp/ko pair; pooled stays in LDS.
__global__ __launch_bounds__(1024) void kpo2(float* __restrict__ ws,
    const float* __restrict__ Wv, const float* __restrict__ bv,
    const float* __restrict__ Wo, const float* __restrict__ bo){
  int b = blockIdx.x; int c = b >> 2, s = b & 3; int t = threadIdx.x;
  __shared__ float red[4][256];
  __shared__ float pl[256];
  int e = t & 255, dsl = t >> 8;
  int h = e >> 5;
  {
    const float* xr = ws + XW_OFF + (size_t)c*8192 + (size_t)(s*8 + h)*256 + dsl*64;
    const float* wv = Wv + (size_t)s*65536 + (size_t)(dsl*64)*256 + e;
    float a = 0.f;
#pragma unroll 8
    for (int d=0; d<64; ++d) a = fmaf(wv[(size_t)d*256], xr[d], a);
    red[dsl][e] = a;
  }
  __syncthreads();
  if (t < 256){
    float rcnt = (c < 10) ? (1.0f/(float)CS) : 0.125f;
    pl[t] = (red[0][t]+red[1][t]+red[2][t]+red[3][t] + bv[s*256 + t]) * rcnt;
  }
  __syncthreads();
  {
    const float* pr = pl + dsl*64;
    const float* wo = Wo + (size_t)s*65536 + (size_t)(dsl*64)*256 + e;
    float o = 0.f;
#pragma unroll 8
    for (int d=0; d<64; ++d) o = fmaf(wo[(size_t)d*256], pr[d], o);
    red[dsl][e] = o;
  }
  __syncthreads();
  if (t < 256)
    ws[OL_OFF + (size_t)c*1024 + s*256 + t] = red[0][t]+red[1][t]+red[2][t]+red[3][t] + bo[s*256 + t];
}

// ---- KFC: Wf1 -> LayerNorm -> GELU -> Wf2 (+bf2). 11 blocks x 1024 (R8-proven).
__global__ __launch_bounds__(1024) void kfc(float* __restrict__ ws,
    const float* __restrict__ Wf1, const float* __restrict__ bf1,
    const float* __restrict__ lng, const float* __restrict__ lnb,
    const float* __restrict__ Wf2, const float* __restrict__ bf2){
  int c = blockIdx.x, t = threadIdx.x;
  __shared__ float oll[1024];
  __shared__ float hp[4][256];
  __shared__ float hl[256];
  __shared__ float fp[4][256];
  __shared__ float rs1[4], rs2[4];
  oll[t] = ws[OL_OFF + (size_t)c*1024 + t];
  __syncthreads();
  int f = t & 255, kq = t >> 8;
  {
    float a = 0.f;
    const float* wf = Wf1 + (size_t)(kq*256)*256 + f;
    const float* ol = oll + kq*256;
#pragma unroll 8
    for (int i=0;i<256;i++) a = fmaf(wf[(size_t)i*256], ol[i], a);
    hp[kq][f] = a;
  }
  __syncthreads();
  float hacc = 0.f;
  if (t < 256){
    hacc = hp[0][t]+hp[1][t]+hp[2][t]+hp[3][t] + bf1[t];
    float s1 = hacc, s2v = hacc*hacc;
    for (int off=32; off>0; off>>=1){ s1 += __shfl_down(s1, off, 64); s2v += __shfl_down(s2v, off, 64); }
    int wid = t>>6, lane = t&63;
    if (lane==0){ rs1[wid]=s1; rs2[wid]=s2v; }
  }
  __syncthreads();
  if (t < 256){
    float S1 = rs1[0]+rs1[1]+rs1[2]+rs1[3];
    float S2 = rs2[0]+rs2[1]+rs2[2]+rs2[3];
    float mu = S1*(1.0f/256.0f);
    float var = S2*(1.0f/256.0f) - mu*mu;
    float rsig = rsqrtf(var + 1e-5f);
    float hn = (hacc - mu)*rsig*lng[t] + lnb[t];
    hl[t] = 0.5f*hn*(1.0f + erff(hn*0.70710678118654752f));   // exact GELU
  }
  __syncthreads();
  {
    float a = 0.f;
    const float* wf = Wf2 + (size_t)(kq*64)*256 + f;
    const float* hh = hl + kq*64;
#pragma unroll
    for (int i=0;i<64;i++) a = fmaf(wf[(size_t)i*256], hh[i], a);
    fp[kq][f] = a;
  }
  __syncthreads();
  if (t < 256)
    ws[CF2_OFF + (size_t)c*256 + t] = fp[0][t]+fp[1][t]+fp[2][t]+fp[3][t] + bf2[t];
}

// ---- KBC3: broadcast finished cluster rows to all nodes. 8192 blocks (R8-proven).
__global__ __launch_bounds__(256) void kbc3(const float* __restrict__ ws, float4* __restrict__ out){
  unsigned bidx = blockIdx.x, t = threadIdx.x;
  unsigned idx = bidx*256u + t;
  unsigned c = (bidx*4u) / (unsigned)CS;   // 3276 % 4 == 0 -> one cluster per block
  __shared__ float4 row[64];
  if (t < 64) row[t] = ((const float4*)(ws + CF2_OFF))[c*64u + t];
  __syncthreads();
  out[idx] = row[t & 63u];
}

extern "C" void kernel_launch(void* const* d_in, const int* in_sizes, int n_in,
                              void* d_out, int out_size, void* d_ws, size_t ws_size,
                              hipStream_t stream) {
  const float* x   = (const float*)d_in[0];
  // d_in[1] edge_index, d_in[2] batch: unused by the reference computation
  const float* Wk  = (const float*)d_in[3];
  const float* bk  = (const float*)d_in[4];
  const float* Wv  = (const float*)d_in[5];
  const float* bv  = (const float*)d_in[6];
  const float* Wo  = (const float*)d_in[7];
  const float* bo  = (const float*)d_in[8];
  const float* pq  = (const float*)d_in[9];
  const float* Wf1 = (const float*)d_in[10];
  const float* bf1 = (const float*)d_in[11];
  const float* lng = (const float*)d_in[12];
  const float* lnb = (const float*)d_in[13];
  const float* Wf2 = (const float*)d_in[14];
  const float* bf2 = (const float*)d_in[15];
  float* ws = (float*)d_ws;
  float4* out = (float4*)d_out;

  hipLaunchKernelGGL(ka,    dim3(33),   dim3(256),  0, stream, Wk, bk, pq, ws);
  hipLaunchKernelGGL(kbd10, dim3(NB),   dim3(512),  0, stream, x, ws);
  hipLaunchKernelGGL(ke2,   dim3(352),  dim3(256),  0, stream, ws);
  hipLaunchKernelGGL(kpo2,  dim3(44),   dim3(1024), 0, stream, ws, Wv, bv, Wo, bo);
  hipLaunchKernelGGL(kfc,   dim3(11),   dim3(1024), 0, stream, ws, Wf1, bf1, lng, lnb, Wf2, bf2);
  hipLaunchKernelGGL(kbc3,  dim3(8192), dim3(256),  0, stream, ws, out);
}

// Round 15
// 60.637 us; speedup vs baseline: 1.1556x; 1.1556x over previous
//
#include <hip/hip_runtime.h>
#include <math.h>

// HierarchicalPooling collapsed pipeline, round 15.
// N=32768, D=256, S=4, H=8, DH=32, CS=3276, C=11.
// R14 lesson: kp+ko and kf1+kf2b fusions regressed +8.3us (narrow wide-block
// kernels latency-exposed; 176-block chain + ~1.5us/launch is better).
// R15: exact R13 revert + bf16 chunk partials (kbd10 store / ke2 read only):
// halves the 17MB+17MB partial round-trip; ke2 still accumulates f32.

namespace {
constexpr int N   = 32768;
constexpr int CS  = 3276;
constexpr int CPC = 52;                // 64-node chunks per full cluster
constexpr int NB  = CPC*10 + 1;        // 521 blocks

// ws layout (float offsets); total ~9.1 MB
constexpr size_t CQ_OFF   = 0;                               // 32
constexpr size_t WQBF_OFF = 32;                              // 1024 uint4 B-fragments
constexpr size_t PART_OFF = WQBF_OFF + 4096;                 // NB*8192 bf16 chunk partials (NB*4096 floats)
constexpr size_t PS_OFF   = PART_OFF + (size_t)NB*4096;      // 11*32 sum-exp (atomic)
constexpr size_t XW_OFF   = PS_OFF + 352;                    // 11*8192 normalized xw
constexpr size_t PL_OFF   = XW_OFF + 90112;                  // 11*1024 pooled
constexpr size_t OL_OFF   = PL_OFF + 11264;                  // 11*1024 out rows
constexpr size_t HP_OFF   = OL_OFF + 11264;                  // 11*4*256 Wf1 partials
constexpr size_t FP_OFF   = HP_OFF + 11264;                  // 11*4*256 Wf2 partials
}

typedef __attribute__((ext_vector_type(8))) short short8;
typedef __attribute__((ext_vector_type(4))) float f32x4;

__device__ __forceinline__ unsigned f2bf(float f){    // f32 -> bf16 bits, RNE
  unsigned u = __float_as_uint(f);
  unsigned r = u + 0x7FFFu + ((u >> 16) & 1u);
  return r >> 16;
}

// ---- KA: wq rows -> bf16 B-fragments (packed via LDS); cq; PS zero. (R10-proven)
__global__ __launch_bounds__(256) void ka(const float* __restrict__ Wk, const float* __restrict__ bk,
                                          const float* __restrict__ pq, float* __restrict__ ws){
  int b = blockIdx.x, t = threadIdx.x;
  const float scale = 0.17677669529663688f;   // 32^-0.5
  if (b < 32){
    __shared__ float row[256];
    int s = b >> 3, h = b & 7;
    const float* wrow = Wk + ((size_t)s<<16) + (size_t)t*256 + h*32;
    const float* q = pq + (s*8 + h)*32;
    float a = 0.f;
#pragma unroll
    for (int j=0;j<32;j++) a = fmaf(wrow[j], q[j], a);
    row[t] = a*scale;
    __syncthreads();
    if (t < 32){
      int ks = t & 7, kg2 = t >> 3;
      const float* src = row + ks*32 + kg2*8;
      uint4 p;
      p.x = f2bf(src[0]) | (f2bf(src[1]) << 16);
      p.y = f2bf(src[2]) | (f2bf(src[3]) << 16);
      p.z = f2bf(src[4]) | (f2bf(src[5]) << 16);
      p.w = f2bf(src[6]) | (f2bf(src[7]) << 16);
      int Nt = b >> 4, l15b = b & 15;
      ((uint4*)(ws + WQBF_OFF))[(size_t)(Nt*8 + ks)*64 + l15b + 16*kg2] = p;
    }
  } else {
    if (t < 32){
      int s = t >> 3, h = t & 7;
      const float* br = bk + s*256 + h*32;
      const float* q = pq + t*32;
      float a = 0.f;
#pragma unroll
      for (int j=0;j<32;j++) a = fmaf(br[j], q[j], a);
      ws[CQ_OFF + t] = a*scale;
    }
    for (int i = t; i < 352; i += 256) ws[PS_OFF + i] = 0.f;   // zero atomic targets
  }
}

// ---- KBD10: MFMA scores + exp + PS atomics + MFMA xw chunk partials. (R13-proven;
// only the partial store is changed to bf16.)
__global__ __launch_bounds__(512,4) void kbd10(const float* __restrict__ x, float* __restrict__ ws){
  int b = blockIdx.x, t = threadIdx.x;
  int c  = (b < 520) ? (b / CPC) : 10;
  int wi = (b < 520) ? (b % CPC) : 0;
  int n0 = c*CS + wi*64;
  int n1 = min(n0 + 64, min((c+1)*CS, N));
  int cnt = n1 - n0;                    // 64, 12 (cluster tails), or 8 (cluster 10)

  __shared__ __align__(16) unsigned short xtb[64*264]; // 33.8KB bf16 tile, row stride 528B
  __shared__ __align__(16) unsigned short swT[32*72];  // 4.6KB bf16 weights [sh][j], stride 144B
  __shared__ float psb[16*32];

  int wv = t >> 6, lane = t & 63;
  int Mt = wv & 3, Nt = wv >> 2;
  int l15 = lane & 15, kg = lane >> 4;
  int arow = Mt*16 + l15;
  uint4 bfr[8];
  const uint4* WQBF4 = (const uint4*)(ws + WQBF_OFF);
#pragma unroll
  for (int ks=0; ks<8; ++ks) bfr[ks] = WQBF4[(size_t)(Nt*8 + ks)*64 + lane];
  float cqv = ws[CQ_OFF + Nt*16 + l15];
  int shc = Nt*16 + l15;

  // stage 64 rows as bf16; rows >= N zero-filled (NaN-safe for pass2 MFMA)
  const float4* X4 = (const float4*)x;
#pragma unroll
  for (int k=0;k<8;k++){
    int f = t + k*512;
    int j = f >> 6, c4 = f & 63;
    float4 v = (n0 + j < N) ? X4[(size_t)(n0+j)*64 + c4] : make_float4(0.f,0.f,0.f,0.f);
    uint2 p;
    p.x = f2bf(v.x) | (f2bf(v.y) << 16);
    p.y = f2bf(v.z) | (f2bf(v.w) << 16);
    *(uint2*)(xtb + j*264 + c4*4) = p;
  }
  __syncthreads();

  // ---- pass 1: scores via 8x mfma_f32_16x16x32_bf16
  f32x4 acc1 = {0.f, 0.f, 0.f, 0.f};
#pragma unroll
  for (int ks=0; ks<8; ++ks){
    union { uint4 q; short8 v; } A, B;
    A.q = *(const uint4*)(xtb + arow*264 + ks*32 + kg*8);
    B.q = bfr[ks];
    acc1 = __builtin_amdgcn_mfma_f32_16x16x32_bf16(A.v, B.v, acc1, 0, 0, 0);
  }
  // epilogue: weights (bf16) -> swT[sh][j]; zero for j >= cnt; chunk sums.
  // C layout: col(sh)=lane&15, row(j)=kg*4+reg.
  {
    float ev[4];
    float s4 = 0.f;
#pragma unroll
    for (int r=0;r<4;r++){
      int jl = Mt*16 + kg*4 + r;
      float e = (jl < cnt) ? __expf(acc1[r] + cqv) : 0.f;
      ev[r] = e; s4 += e;
    }
    uint2 wp;
    wp.x = f2bf(ev[0]) | (f2bf(ev[1]) << 16);
    wp.y = f2bf(ev[2]) | (f2bf(ev[3]) << 16);
    *(uint2*)(swT + (size_t)shc*72 + Mt*16 + kg*4) = wp;
    psb[(Mt*4 + kg)*32 + shc] = s4;
  }
  __syncthreads();
  if (t < 32){
    float S = 0.f;
#pragma unroll
    for (int k=0;k<16;k++) S += psb[k*32 + t];
    unsafeAtomicAdd(ws + PS_OFF + (size_t)c*32 + t, S);
  }

  // ---- pass 2: O[sh][d] = sum_j w[j][sh]*x[j][d] via MFMA.
  int Mt2 = wv & 1, Nq = wv >> 1;
  union FR { uint4 q; short8 v; };
  FR a0, a1;
  a0.q = *(const uint4*)(swT + (size_t)(Mt2*16 + l15)*72 + kg*8);
  a1.q = *(const uint4*)(swT + (size_t)(Mt2*16 + l15)*72 + 32 + kg*8);
  unsigned xb = (unsigned)(size_t)&xtb[0];
  unsigned va = xb + (unsigned)(kg*4224 + (l15>>2)*528 + (l15&3)*8 + Nq*128);
  unsigned long long tr[4][2][2];
#pragma unroll
  for (int i=0;i<4;i++){
#pragma unroll
    for (int k2=0;k2<2;k2++){
      asm volatile("ds_read_b64_tr_b16 %0, %2 offset:%c3\n\t"
                   "ds_read_b64_tr_b16 %1, %2 offset:%c4"
                   : "=v"(tr[i][k2][0]), "=v"(tr[i][k2][1])
                   : "v"(va), "i"(i*32 + k2*16896), "i"(i*32 + k2*16896 + 2112));
    }
  }
  asm volatile("s_waitcnt lgkmcnt(0)" ::: "memory");
  __builtin_amdgcn_sched_barrier(0);
  f32x4 o[4] = {{0.f,0.f,0.f,0.f},{0.f,0.f,0.f,0.f},{0.f,0.f,0.f,0.f},{0.f,0.f,0.f,0.f}};
#pragma unroll
  for (int i=0;i<4;i++){
#pragma unroll
    for (int k2=0;k2<2;k2++){
      FR Bf;
      Bf.q.x = (unsigned)(tr[i][k2][0] & 0xffffffffULL);
      Bf.q.y = (unsigned)(tr[i][k2][0] >> 32);
      Bf.q.z = (unsigned)(tr[i][k2][1] & 0xffffffffULL);
      Bf.q.w = (unsigned)(tr[i][k2][1] >> 32);
      o[i] = __builtin_amdgcn_mfma_f32_16x16x32_bf16(k2 ? a1.v : a0.v, Bf.v, o[i], 0, 0, 0);
    }
  }
  // store partials as bf16: C layout col(d)=l15, row(sh)=kg*4+r
  unsigned short* pr = (unsigned short*)(ws + PART_OFF) + (size_t)b*8192;
#pragma unroll
  for (int i=0;i<4;i++){
    int dcol = Nq*64 + i*16 + l15;
#pragma unroll
    for (int r=0;r<4;r++)
      pr[(size_t)(Mt2*16 + kg*4 + r)*256 + dcol] = (unsigned short)f2bf(o[i][r]);
  }
}

// ---- KE2: sum bf16 chunk partials (f32 accum) / PS -> xw[c][sh][d]. 352 blocks.
__global__ __launch_bounds__(256) void ke2(float* __restrict__ ws){
  int b = blockIdx.x, t = threadIdx.x;
  int c = b >> 5, sh = b & 31;
  int nch = (c < 10) ? CPC : 1;
  int cb  = (c < 10) ? c*CPC : 520;
  float rden = 1.0f / ws[PS_OFF + (size_t)c*32 + sh];
  const unsigned short* part = (const unsigned short*)(ws + PART_OFF) + (size_t)sh*256 + t;
  float a = 0.f;
  for (int k=0;k<nch;k++)
    a += __uint_as_float(((unsigned)part[(size_t)(cb+k)*8192]) << 16);
  ws[XW_OFF + (size_t)c*8192 + (size_t)sh*256 + t] = a * rden;
}

// ---- KP: pooled per (c,s,eq). 176 blocks (R7-proven).
__global__ __launch_bounds__(256) void kp(float* __restrict__ ws,
    const float* __restrict__ Wv, const float* __restrict__ bv){
  int b = blockIdx.x; int c = b >> 4, rem = b & 15, s = rem >> 2, eq = rem & 3;
  int t = threadIdx.x, e64 = t & 63, dq = t >> 6;
  int e = eq*64 + e64, h = e >> 5;
  const float* xr = ws + XW_OFF + (size_t)c*8192 + (size_t)(s*8 + h)*256 + dq*64;
  const float* wv = Wv + (size_t)s*65536 + (size_t)(dq*64)*256 + e;
  float a = 0.f;
#pragma unroll 8
  for (int d=0; d<64; ++d) a = fmaf(wv[(size_t)d*256], xr[d], a);
  __shared__ float red[4][64];
  red[dq][e64] = a;
  __syncthreads();
  if (t < 64){
    float rcnt = (c < 10) ? (1.0f/(float)CS) : 0.125f;
    float p = (red[0][t]+red[1][t]+red[2][t]+red[3][t] + bv[s*256 + eq*64 + t]) * rcnt;
    ws[PL_OFF + (size_t)c*1024 + s*256 + eq*64 + t] = p;
  }
}

// ---- KO: out per (c,s,eq) = pooled @ Wo + bo. 176 blocks (R7-proven).
__global__ __launch_bounds__(256) void ko(float* __restrict__ ws,
    const float* __restrict__ Wo, const float* __restrict__ bo){
  int b = blockIdx.x; int c = b >> 4, rem = b & 15, s = rem >> 2, eq = rem & 3;
  int t = threadIdx.x, e64 = t & 63, dq = t >> 6;
  int e = eq*64 + e64;
  const float* pr = ws + PL_OFF + (size_t)c*1024 + s*256 + dq*64;
  const float* wo = Wo + (size_t)s*65536 + (size_t)(dq*64)*256 + e;
  float a = 0.f;
#pragma unroll 8
  for (int d=0; d<64; ++d) a = fmaf(wo[(size_t)d*256], pr[d], a);
  __shared__ float red[4][64];
  red[dq][e64] = a;
  __syncthreads();
  if (t < 64)
    ws[OL_OFF + (size_t)c*1024 + s*256 + eq*64 + t] =
      red[0][t]+red[1][t]+red[2][t]+red[3][t] + bo[s*256 + eq*64 + t];
}

// ---- KF1: h partials: block (c, fq, kq). 176 blocks (R7-proven).
__global__ __launch_bounds__(256) void kf1(const float* __restrict__ Wf1, float* __restrict__ ws){
  int b = blockIdx.x; int c = b >> 4, fq = (b >> 2) & 3, kq = b & 3;
  int t = threadIdx.x, f64 = t & 63, ks = t >> 6;
  const float* ol = ws + OL_OFF + (size_t)c*1024 + kq*256 + ks*64;
  const float* wf = Wf1 + (size_t)(kq*256 + ks*64)*256 + fq*64 + f64;
  float a = 0.f;
#pragma unroll 8
  for (int i=0; i<64; ++i) a = fmaf(wf[(size_t)i*256], ol[i], a);
  __shared__ float red[4][64];
  red[ks][f64] = a;
  __syncthreads();
  if (t < 64)
    ws[HP_OFF + (size_t)(c*4 + kq)*256 + fq*64 + t] = red[0][t]+red[1][t]+red[2][t]+red[3][t];
}

// ---- KF2B: (LN+GELU recomputed in-block from HP) -> Wf2 partials. 176 blocks (R11-proven).
__global__ __launch_bounds__(256) void kf2b(const float* __restrict__ Wf2, float* __restrict__ ws,
    const float* __restrict__ bf1, const float* __restrict__ lng, const float* __restrict__ lnb){
  int b = blockIdx.x; int c = b >> 4, gq = (b >> 2) & 3, kq = b & 3;
  int t = threadIdx.x;
  __shared__ float hl[256];
  __shared__ float rs1[4], rs2[4];
  float hacc = bf1[t];
#pragma unroll
  for (int q=0;q<4;q++) hacc += ws[HP_OFF + (size_t)(c*4+q)*256 + t];
  float s1 = hacc, s2v = hacc*hacc;
  for (int off=32; off>0; off>>=1){ s1 += __shfl_down(s1, off, 64); s2v += __shfl_down(s2v, off, 64); }
  int wid = t>>6, lane = t&63;
  if (lane==0){ rs1[wid]=s1; rs2[wid]=s2v; }
  __syncthreads();
  float S1 = rs1[0]+rs1[1]+rs1[2]+rs1[3];
  float S2 = rs2[0]+rs2[1]+rs2[2]+rs2[3];
  float mu = S1*(1.0f/256.0f);
  float var = S2*(1.0f/256.0f) - mu*mu;
  float rsig = rsqrtf(var + 1e-5f);
  float hn = (hacc - mu)*rsig*lng[t] + lnb[t];
  hl[t] = 0.5f*hn*(1.0f + erff(hn*0.70710678118654752f));   // exact GELU
  __syncthreads();
  int g64 = t & 63, ks = t >> 6;
  const float* hh = hl + kq*64 + ks*16;
  const float* wf = Wf2 + (size_t)(kq*64 + ks*16)*256 + gq*64 + g64;
  float a = 0.f;
#pragma unroll
  for (int i=0; i<16; ++i) a = fmaf(wf[(size_t)i*256], hh[i], a);
  __shared__ float red[4][64];
  red[ks][g64] = a;
  __syncthreads();
  if (t < 64)
    ws[FP_OFF + (size_t)(c*4 + kq)*256 + gq*64 + t] = red[0][t]+red[1][t]+red[2][t]+red[3][t];
}

// ---- KBC2: sum Wf2 partials + bf2 once per block, broadcast. 8192 blocks (R7-proven).
__global__ __launch_bounds__(256) void kbc2(const float* __restrict__ ws, float4* __restrict__ out,
                                            const float* __restrict__ bf2){
  unsigned bidx = blockIdx.x, t = threadIdx.x;
  unsigned idx = bidx*256u + t;
  unsigned c = (bidx*4u) / (unsigned)CS;   // 3276 % 4 == 0 -> one cluster per block
  __shared__ float4 row[64];
  if (t < 64){
    const float4* FP4 = (const float4*)(ws + FP_OFF);
    float4 s0 = FP4[(c*4+0)*64 + t];
    float4 s1 = FP4[(c*4+1)*64 + t];
    float4 s2 = FP4[(c*4+2)*64 + t];
    float4 s3 = FP4[(c*4+3)*64 + t];
    float4 bb = ((const float4*)bf2)[t];
    row[t] = make_float4(s0.x+s1.x+s2.x+s3.x+bb.x, s0.y+s1.y+s2.y+s3.y+bb.y,
                         s0.z+s1.z+s2.z+s3.z+bb.z, s0.w+s1.w+s2.w+s3.w+bb.w);
  }
  __syncthreads();
  out[idx] = row[t & 63u];
}

extern "C" void kernel_launch(void* const* d_in, const int* in_sizes, int n_in,
                              void* d_out, int out_size, void* d_ws, size_t ws_size,
                              hipStream_t stream) {
  const float* x   = (const float*)d_in[0];
  // d_in[1] edge_index, d_in[2] batch: unused by the reference computation
  const float* Wk  = (const float*)d_in[3];
  const float* bk  = (const float*)d_in[4];
  const float* Wv  = (const float*)d_in[5];
  const float* bv  = (const float*)d_in[6];
  const float* Wo  = (const float*)d_in[7];
  const float* bo  = (const float*)d_in[8];
  const float* pq  = (const float*)d_in[9];
  const float* Wf1 = (const float*)d_in[10];
  const float* bf1 = (const float*)d_in[11];
  const float* lng = (const float*)d_in[12];
  const float* lnb = (const float*)d_in[13];
  const float* Wf2 = (const float*)d_in[14];
  const float* bf2 = (const float*)d_in[15];
  float* ws = (float*)d_ws;
  float4* out = (float4*)d_out;

  hipLaunchKernelGGL(ka,    dim3(33),   dim3(256), 0, stream, Wk, bk, pq, ws);
  hipLaunchKernelGGL(kbd10, dim3(NB),   dim3(512), 0, stream, x, ws);
  hipLaunchKernelGGL(ke2,   dim3(352),  dim3(256), 0, stream, ws);
  hipLaunchKernelGGL(kp,    dim3(176),  dim3(256), 0, stream, ws, Wv, bv);
  hipLaunchKernelGGL(ko,    dim3(176),  dim3(256), 0, stream, ws, Wo, bo);
  hipLaunchKernelGGL(kf1,   dim3(176),  dim3(256), 0, stream, Wf1, ws);
  hipLaunchKernelGGL(kf2b,  dim3(176),  dim3(256), 0, stream, Wf2, ws, bf1, lng, lnb);
  hipLaunchKernelGGL(kbc2,  dim3(8192), dim3(256), 0, stream, ws, out, bf2);
}